// Round 2
// baseline (621.758 us; speedup 1.0000x reference)
//
#include <hip/hip_runtime.h>
#include <hip/hip_bf16.h>
#include <stdint.h>

#define S_DIM 512
#define R_DIM 384
#define CMSA 64
#define CZ 128
#define HH 8
#define CHID 32
#define HC 256
#define INF_V 1e8f
#define EPS_V 1e-5f

typedef __bf16 bf16x8 __attribute__((ext_vector_type(8)));
typedef float f32x4 __attribute__((ext_vector_type(4)));

__device__ __forceinline__ unsigned short f2bf(float f) {
  __hip_bfloat16 h = __float2bfloat16(f);
  return *reinterpret_cast<unsigned short*>(&h);
}
__device__ __forceinline__ float bf2f(unsigned short u) {
  __hip_bfloat16 h;
  *reinterpret_cast<unsigned short*>(&h) = u;
  return __bfloat162float(h);
}
__device__ __forceinline__ int4 pack8(const unsigned short* u) {
  int4 p;
  p.x = (int)u[0] | ((int)u[1] << 16);
  p.y = (int)u[2] | ((int)u[3] << 16);
  p.z = (int)u[4] | ((int)u[5] << 16);
  p.w = (int)u[6] | ((int)u[7] << 16);
  return p;
}

// ---------------------------------------------------------------------------
// K1: pair bias  b[i,h,j] = LN(z[i,j,:]) @ w_b[:,h] + INF*(z_mask-1)
// one wave per (i,j); b_ws layout [i][h][j] fp32
// ---------------------------------------------------------------------------
__global__ __launch_bounds__(256) void k_bias(
    const float* __restrict__ z, const float* __restrict__ z_mask,
    const float* __restrict__ lnw, const float* __restrict__ lnb,
    const float* __restrict__ w_b, float* __restrict__ b_out) {
  int gw = (blockIdx.x * 256 + threadIdx.x) >> 6;
  int lane = threadIdx.x & 63;
  int i = gw / R_DIM, j = gw - i * R_DIM;
  const float* zp = z + (size_t)gw * CZ;
  float x0 = zp[lane], x1 = zp[lane + 64];
  float s = x0 + x1, s2 = x0 * x0 + x1 * x1;
#pragma unroll
  for (int d = 1; d < 64; d <<= 1) { s += __shfl_xor(s, d); s2 += __shfl_xor(s2, d); }
  float mu = s * (1.0f / CZ);
  float var = s2 * (1.0f / CZ) - mu * mu;
  float rs = rsqrtf(var + EPS_V);
  float n0 = (x0 - mu) * rs * lnw[lane] + lnb[lane];
  float n1 = (x1 - mu) * rs * lnw[lane + 64] + lnb[lane + 64];
  float madd = INF_V * (z_mask[gw] - 1.0f);
#pragma unroll
  for (int h = 0; h < HH; ++h) {
    float p = n0 * w_b[lane * HH + h] + n1 * w_b[(lane + 64) * HH + h];
#pragma unroll
    for (int d = 1; d < 64; d <<= 1) p += __shfl_xor(p, d);
    if (lane == 0) b_out[((size_t)i * HH + h) * R_DIM + j] = p + madd;
  }
}

// ---------------------------------------------------------------------------
// K2: softmax over j for each (i,h); write bf16 w_bf[h][i][j]
// ---------------------------------------------------------------------------
__global__ __launch_bounds__(128) void k_softmax(
    const float* __restrict__ b_in, unsigned short* __restrict__ w_bf) {
  int row = blockIdx.x;              // i*8 + h
  int i = row / HH, h = row - i * HH;
  const float* bp = b_in + (size_t)row * R_DIM;
  int t = threadIdx.x;
  float v[3];
  float mx = -INFINITY;
#pragma unroll
  for (int k = 0; k < 3; ++k) { v[k] = bp[t + 128 * k]; mx = fmaxf(mx, v[k]); }
  __shared__ float red[128];
  red[t] = mx; __syncthreads();
  for (int off = 64; off > 0; off >>= 1) {
    if (t < off) red[t] = fmaxf(red[t], red[t + off]);
    __syncthreads();
  }
  mx = red[0]; __syncthreads();
  float sum = 0.f;
#pragma unroll
  for (int k = 0; k < 3; ++k) { v[k] = __expf(v[k] - mx); sum += v[k]; }
  red[t] = sum; __syncthreads();
  for (int off = 64; off > 0; off >>= 1) {
    if (t < off) red[t] += red[t + off];
    __syncthreads();
  }
  float inv = 1.0f / red[0];
  unsigned short* wp = w_bf + ((size_t)h * R_DIM + i) * R_DIM;
#pragma unroll
  for (int k = 0; k < 3; ++k) wp[t + 128 * k] = f2bf(v[k] * inv);
}

// ---------------------------------------------------------------------------
// K3 (MFMA): v = (LN(m)@w_v)*mask -> Vt[s][hc][j] bf16 (LDS-transposed store)
//            g = sigmoid(LN(m)@w_g) -> g_ws[s][res][hc] bf16 (direct store)
// block = 128 rows (one s, res-chunk of 128), 512 thr.
// LDS: A[128 res][64 cm] bf16 swz | wTv/wTg[256 hc][64 cm] bf16 swz |
//      T[256 hc][res pad 272B] | mask[128] f32
// ---------------------------------------------------------------------------
__global__ __launch_bounds__(512) void k_vg(
    const float* __restrict__ m, const float* __restrict__ msa_mask,
    const float* __restrict__ lnw, const float* __restrict__ lnb,
    const float* __restrict__ w_v, const float* __restrict__ w_g,
    unsigned short* __restrict__ Vt, unsigned short* __restrict__ g_ws) {
  extern __shared__ char lds[];
  const int A_OFF = 0;         // 16384
  const int WV_OFF = 16384;    // 32768
  const int WG_OFF = 49152;    // 32768
  const int T_OFF = 81920;     // 256*272 = 69632
  const int M_OFF = 151552;    // 512
  int tid = threadIdx.x, l = tid & 63, wv = tid >> 6;
  int b = blockIdx.x;
  int s = b / 3;
  int res0 = (b % 3) * 128;
  size_t row0 = (size_t)s * R_DIM + res0;

  if (tid < 128) *reinterpret_cast<float*>(&lds[M_OFF + tid * 4]) = msa_mask[row0 + tid];

  // stage w_v^T, w_g^T as bf16 [hc][cm], XOR-swizzled (8 slots/row)
  for (int it = 0; it < 4; ++it) {
    int G = it * 512 + tid;
    int hcr = G >> 3, slot = G & 7;
    unsigned short uv[8], ug[8];
#pragma unroll
    for (int e = 0; e < 8; ++e) {
      uv[e] = f2bf(w_v[(size_t)(slot * 8 + e) * HC + hcr]);
      ug[e] = f2bf(w_g[(size_t)(slot * 8 + e) * HC + hcr]);
    }
    int swz = hcr * 128 + ((slot ^ (hcr & 7)) << 4);
    *reinterpret_cast<int4*>(&lds[WV_OFF + swz]) = pack8(uv);
    *reinterpret_cast<int4*>(&lds[WG_OFF + swz]) = pack8(ug);
  }

  // LN(m) -> A-lds bf16 swizzled
  float lw = lnw[l], lbv = lnb[l];
  for (int q = 0; q < 16; ++q) {
    int r = wv * 16 + q;
    float x = m[(row0 + r) * CMSA + l];
    float sm = x, s2 = x * x;
#pragma unroll
    for (int d = 1; d < 64; d <<= 1) { sm += __shfl_xor(sm, d); s2 += __shfl_xor(s2, d); }
    float mu = sm * (1.f / 64.f);
    float var = s2 * (1.f / 64.f) - mu * mu;
    float nv = (x - mu) * rsqrtf(var + EPS_V) * lw + lbv;
    *reinterpret_cast<unsigned short*>(
        &lds[A_OFF + r * 128 + (((l >> 3) ^ (r & 7)) << 4) + (l & 7) * 2]) = f2bf(nv);
  }
  __syncthreads();

  f32x4 zz = {0.f, 0.f, 0.f, 0.f};
  // ---- v phase: D[res][hc] = LN @ w_v ----
  f32x4 vacc[2][8];
#pragma unroll
  for (int a = 0; a < 2; ++a)
#pragma unroll
    for (int n = 0; n < 8; ++n) vacc[a][n] = zz;
#pragma unroll
  for (int kc = 0; kc < 2; ++kc) {
    bf16x8 af[2], bfv[8];
#pragma unroll
    for (int mf = 0; mf < 2; ++mf) {
      int row = ((wv & 3) * 2 + mf) * 16 + (l & 15);
      af[mf] = *reinterpret_cast<const bf16x8*>(
          &lds[A_OFF + row * 128 + (((kc * 4 + (l >> 4)) ^ (row & 7)) << 4)]);
    }
#pragma unroll
    for (int nf = 0; nf < 8; ++nf) {
      int row = ((wv >> 2) * 8 + nf) * 16 + (l & 15);
      bfv[nf] = *reinterpret_cast<const bf16x8*>(
          &lds[WV_OFF + row * 128 + (((kc * 4 + (l >> 4)) ^ (row & 7)) << 4)]);
    }
#pragma unroll
    for (int mf = 0; mf < 2; ++mf)
#pragma unroll
      for (int nf = 0; nf < 8; ++nf)
        vacc[mf][nf] = __builtin_amdgcn_mfma_f32_16x16x32_bf16(af[mf], bfv[nf], vacc[mf][nf], 0, 0, 0);
  }
  // epilogue v: mask, bf16, T[hc][res] (row stride 272B)
#pragma unroll
  for (int mf = 0; mf < 2; ++mf) {
    int resb = ((wv & 3) * 2 + mf) * 16 + (l >> 4) * 4;
    float4 mk = *reinterpret_cast<const float4*>(&lds[M_OFF + resb * 4]);
#pragma unroll
    for (int nf = 0; nf < 8; ++nf) {
      int hc = ((wv >> 2) * 8 + nf) * 16 + (l & 15);
      ushort4 o;
      o.x = f2bf(vacc[mf][nf][0] * mk.x);
      o.y = f2bf(vacc[mf][nf][1] * mk.y);
      o.z = f2bf(vacc[mf][nf][2] * mk.z);
      o.w = f2bf(vacc[mf][nf][3] * mk.w);
      *reinterpret_cast<ushort4*>(&lds[T_OFF + hc * 272 + resb * 2]) = o;
    }
  }
  __syncthreads();
  // coalesced Vt store: Vt[(s*256+hc)*384 + res0 + ...]
  for (int it = 0; it < 8; ++it) {
    int G = it * 512 + tid;
    int hc = G >> 4, gi = G & 15;
    int4 d = *reinterpret_cast<const int4*>(&lds[T_OFF + hc * 272 + gi * 16]);
    *reinterpret_cast<int4*>(&Vt[((size_t)s * HC + hc) * R_DIM + res0 + gi * 8]) = d;
  }

  // ---- g phase: sigmoid(LN @ w_g), direct store g_ws[s][res][hc] ----
  f32x4 gacc[2][8];
#pragma unroll
  for (int a = 0; a < 2; ++a)
#pragma unroll
    for (int n = 0; n < 8; ++n) gacc[a][n] = zz;
#pragma unroll
  for (int kc = 0; kc < 2; ++kc) {
    bf16x8 af[2], bfg[8];
#pragma unroll
    for (int mf = 0; mf < 2; ++mf) {
      int row = ((wv & 3) * 2 + mf) * 16 + (l & 15);
      af[mf] = *reinterpret_cast<const bf16x8*>(
          &lds[A_OFF + row * 128 + (((kc * 4 + (l >> 4)) ^ (row & 7)) << 4)]);
    }
#pragma unroll
    for (int nf = 0; nf < 8; ++nf) {
      int row = ((wv >> 2) * 8 + nf) * 16 + (l & 15);
      bfg[nf] = *reinterpret_cast<const bf16x8*>(
          &lds[WG_OFF + row * 128 + (((kc * 4 + (l >> 4)) ^ (row & 7)) << 4)]);
    }
#pragma unroll
    for (int mf = 0; mf < 2; ++mf)
#pragma unroll
      for (int nf = 0; nf < 8; ++nf)
        gacc[mf][nf] = __builtin_amdgcn_mfma_f32_16x16x32_bf16(af[mf], bfg[nf], gacc[mf][nf], 0, 0, 0);
  }
#pragma unroll
  for (int mf = 0; mf < 2; ++mf)
#pragma unroll
    for (int nf = 0; nf < 8; ++nf) {
      int hc = ((wv >> 2) * 8 + nf) * 16 + (l & 15);
#pragma unroll
      for (int reg = 0; reg < 4; ++reg) {
        int res = ((wv & 3) * 2 + mf) * 16 + (l >> 4) * 4 + reg;
        float sg = 1.f / (1.f + __expf(-gacc[mf][nf][reg]));
        g_ws[(row0 + res) * HC + hc] = f2bf(sg);  // 16-lane 32B runs
      }
    }
}

// ---------------------------------------------------------------------------
// K4 (MFMA, fused): per block (8 s, 96 i), loop h:
//   einsum o^T[(sl,c)][i] = Vt-tile @ w_bf-tile  (dbuf reg-staged LDS, swz)
//   gate with g_ws, P-lds[768 rows (sl,i)][32 c]
//   proj MFMA: out-acc += P @ w_o^T[h-slice]  (acc in regs across heads)
// ---------------------------------------------------------------------------
__global__ __launch_bounds__(512) void k_wavg(
    const unsigned short* __restrict__ Vt, const unsigned short* __restrict__ g_ws,
    const unsigned short* __restrict__ w_bf, const float* __restrict__ w_o,
    float* __restrict__ out) {
  extern __shared__ char lds[];
  const int A_OFF = 0;       // 2 x 16384
  const int B_OFF = 32768;   // 2 x 6144
  const int P_OFF = 45056;   // 49152
  const int W_OFF = 94208;   // 32768
  int tid = threadIdx.x, l = tid & 63, wv = tid >> 6;
  int bs = blockIdx.x >> 2, bi = blockIdx.x & 3;
  int s0 = bs * 8, i0 = bi * 96;

  // stage w_o^T bf16 [64 l][256 hc], 32 slots/row, XOR (lrow&7)
  for (int it = 0; it < 4; ++it) {
    int G = it * 512 + tid;
    int lrow = G >> 5, slot = G & 31;
    unsigned short u[8];
#pragma unroll
    for (int e = 0; e < 8; ++e) u[e] = f2bf(w_o[(size_t)(slot * 8 + e) * CMSA + lrow]);
    *reinterpret_cast<int4*>(&lds[W_OFF + lrow * 512 + ((slot ^ (lrow & 7)) << 4)]) = pack8(u);
  }

  // staging constants (A: 1024 granules = 2/thread; B: 384 granules)
  int slotg = tid & 3;
  int rA0 = tid >> 2, rA1 = 128 + (tid >> 2);
  size_t vtb0 = ((size_t)(s0 + (rA0 >> 5)) * HC + (rA0 & 31)) * R_DIM + slotg * 8;
  size_t vtb1 = ((size_t)(s0 + (rA1 >> 5)) * HC + (rA1 & 31)) * R_DIM + slotg * 8;
  int ldsA0 = rA0 * 64 + ((slotg ^ (rA0 & 3)) << 4);
  int ldsA1 = rA1 * 64 + ((slotg ^ (rA1 & 3)) << 4);
  int rB = tid >> 2;
  size_t wbase = (size_t)(i0 + rB) * R_DIM + slotg * 8;
  int ldsB = rB * 64 + ((slotg ^ (rB & 3)) << 4);

  int aoff[4], boff[3], poff[6];
#pragma unroll
  for (int mf = 0; mf < 4; ++mf) {
    int row = ((wv & 3) * 4 + mf) * 16 + (l & 15);
    aoff[mf] = row * 64 + (((l >> 4) ^ (row & 3)) << 4);
  }
#pragma unroll
  for (int nf = 0; nf < 3; ++nf) {
    int row = ((wv >> 2) * 3 + nf) * 16 + (l & 15);
    boff[nf] = row * 64 + (((l >> 4) ^ (row & 3)) << 4);
  }
#pragma unroll
  for (int mf = 0; mf < 6; ++mf) {
    int row = (wv * 6 + mf) * 16 + (l & 15);
    poff[mf] = row * 64 + (((l >> 4) ^ (row & 3)) << 4);
  }

  f32x4 zz = {0.f, 0.f, 0.f, 0.f};
  f32x4 pacc[6][4];
#pragma unroll
  for (int a = 0; a < 6; ++a)
#pragma unroll
    for (int n = 0; n < 4; ++n) pacc[a][n] = zz;

  for (int h = 0; h < 8; ++h) {
    const unsigned short* VtA = Vt + (size_t)h * 32 * R_DIM;
    const unsigned short* WB = w_bf + (size_t)h * R_DIM * R_DIM;
    f32x4 acc[4][3];
#pragma unroll
    for (int a = 0; a < 4; ++a)
#pragma unroll
      for (int n = 0; n < 3; ++n) acc[a][n] = zz;

    { // prologue: stage k-step 0 into buf 0
      int4 va0 = *reinterpret_cast<const int4*>(VtA + vtb0);
      int4 va1 = *reinterpret_cast<const int4*>(VtA + vtb1);
      int4 vb;
      if (tid < 384) vb = *reinterpret_cast<const int4*>(WB + wbase);
      *reinterpret_cast<int4*>(&lds[A_OFF + ldsA0]) = va0;
      *reinterpret_cast<int4*>(&lds[A_OFF + ldsA1]) = va1;
      if (tid < 384) *reinterpret_cast<int4*>(&lds[B_OFF + ldsB]) = vb;
    }
    __syncthreads();

    for (int t = 0; t < 12; ++t) {
      int cur = t & 1;
      int4 va0, va1, vb;
      if (t < 11) {
        int j0n = (t + 1) * 32;
        va0 = *reinterpret_cast<const int4*>(VtA + vtb0 + j0n);
        va1 = *reinterpret_cast<const int4*>(VtA + vtb1 + j0n);
        if (tid < 384) vb = *reinterpret_cast<const int4*>(WB + wbase + j0n);
      }
      const char* ab = &lds[A_OFF + cur * 16384];
      const char* bb = &lds[B_OFF + cur * 6144];
      bf16x8 af[4], bfr[3];
#pragma unroll
      for (int mf = 0; mf < 4; ++mf) af[mf] = *reinterpret_cast<const bf16x8*>(ab + aoff[mf]);
#pragma unroll
      for (int nf = 0; nf < 3; ++nf) bfr[nf] = *reinterpret_cast<const bf16x8*>(bb + boff[nf]);
#pragma unroll
      for (int mf = 0; mf < 4; ++mf)
#pragma unroll
        for (int nf = 0; nf < 3; ++nf)
          acc[mf][nf] = __builtin_amdgcn_mfma_f32_16x16x32_bf16(af[mf], bfr[nf], acc[mf][nf], 0, 0, 0);
      if (t < 11) {
        int nxt = cur ^ 1;
        *reinterpret_cast<int4*>(&lds[A_OFF + nxt * 16384 + ldsA0]) = va0;
        *reinterpret_cast<int4*>(&lds[A_OFF + nxt * 16384 + ldsA1]) = va1;
        if (tid < 384) *reinterpret_cast<int4*>(&lds[B_OFF + nxt * 6144 + ldsB]) = vb;
      }
      __syncthreads();
    }

    // gate + P write: P[prow = sl*96+il][c], 64B rows, XOR (prow&3)
#pragma unroll
    for (int mf = 0; mf < 4; ++mf) {
      int MT = (wv & 3) * 4 + mf;
      int sl = MT >> 1;
      int c0 = (MT & 1) * 16 + (l >> 4) * 4;
#pragma unroll
      for (int nf = 0; nf < 3; ++nf) {
        int il = ((wv >> 2) * 3 + nf) * 16 + (l & 15);
        size_t gidx = ((size_t)(s0 + sl) * R_DIM + i0 + il) * HC + h * 32 + c0;
        ushort4 g4 = *reinterpret_cast<const ushort4*>(g_ws + gidx);
        int prow = sl * 96 + il;
        ushort4 og;
        og.x = f2bf(acc[mf][nf][0] * bf2f(g4.x));
        og.y = f2bf(acc[mf][nf][1] * bf2f(g4.y));
        og.z = f2bf(acc[mf][nf][2] * bf2f(g4.z));
        og.w = f2bf(acc[mf][nf][3] * bf2f(g4.w));
        *reinterpret_cast<ushort4*>(
            &lds[P_OFF + prow * 64 + (((c0 >> 3) ^ (prow & 3)) << 4) + (c0 & 7) * 2]) = og;
      }
    }
    __syncthreads();

    // projection: pacc += P @ w_oT[h-slice]
    {
      bf16x8 pa[6], bw[4];
#pragma unroll
      for (int nt = 0; nt < 4; ++nt) {
        int lrow = nt * 16 + (l & 15);
        bw[nt] = *reinterpret_cast<const bf16x8*>(
            &lds[W_OFF + lrow * 512 + (((h * 4 + (l >> 4)) ^ (lrow & 7)) << 4)]);
      }
#pragma unroll
      for (int mf = 0; mf < 6; ++mf) pa[mf] = *reinterpret_cast<const bf16x8*>(&lds[P_OFF + poff[mf]]);
#pragma unroll
      for (int mf = 0; mf < 6; ++mf)
#pragma unroll
        for (int nt = 0; nt < 4; ++nt)
          pacc[mf][nt] = __builtin_amdgcn_mfma_f32_16x16x32_bf16(pa[mf], bw[nt], pacc[mf][nt], 0, 0, 0);
    }
    __syncthreads();
  }

  // final store: out[(s0+sl)*384 + i0+il][l-col] fp32, 64B runs
#pragma unroll
  for (int mf = 0; mf < 6; ++mf) {
#pragma unroll
    for (int reg = 0; reg < 4; ++reg) {
      int prow = (wv * 6 + mf) * 16 + (l >> 4) * 4 + reg;
      int sl = prow / 96;
      int il = prow - sl * 96;
      size_t orow = (size_t)(s0 + sl) * R_DIM + i0 + il;
#pragma unroll
      for (int nt = 0; nt < 4; ++nt)
        out[orow * CMSA + nt * 16 + (l & 15)] = pacc[mf][nt][reg];
    }
  }
}

// ---------------------------------------------------------------------------
extern "C" void kernel_launch(void* const* d_in, const int* in_sizes, int n_in,
                              void* d_out, int out_size, void* d_ws, size_t ws_size,
                              hipStream_t stream) {
  (void)in_sizes; (void)n_in; (void)out_size; (void)ws_size;
  const float* m        = (const float*)d_in[0];
  const float* z        = (const float*)d_in[1];
  const float* msa_mask = (const float*)d_in[2];
  const float* z_mask   = (const float*)d_in[3];
  const float* ln_m_w   = (const float*)d_in[4];
  const float* ln_m_b   = (const float*)d_in[5];
  const float* ln_z_w   = (const float*)d_in[6];
  const float* ln_z_b   = (const float*)d_in[7];
  const float* w_v      = (const float*)d_in[8];
  const float* w_g      = (const float*)d_in[9];
  const float* w_b      = (const float*)d_in[10];
  const float* w_o      = (const float*)d_in[11];
  float* out = (float*)d_out;

  char* ws = (char*)d_ws;
  unsigned short* Vt   = (unsigned short*)ws;                     // 100,663,296 B
  unsigned short* g_ws = (unsigned short*)(ws + 100663296ull);    // 100,663,296 B
  float*          b_ws = (float*)(ws + 201326592ull);             //   4,718,592 B
  unsigned short* w_bf = (unsigned short*)(ws + 206045184ull);    //   2,359,296 B

  k_bias<<<dim3(R_DIM * R_DIM / 4), dim3(256), 0, stream>>>(
      z, z_mask, ln_z_w, ln_z_b, w_b, b_ws);
  k_softmax<<<dim3(R_DIM * HH), dim3(128), 0, stream>>>(b_ws, w_bf);
  k_vg<<<dim3(S_DIM * R_DIM / 128), dim3(512), 152064, stream>>>(
      m, msa_mask, ln_m_w, ln_m_b, w_v, w_g, Vt, g_ws);
  k_wavg<<<dim3(256), dim3(512), 126976, stream>>>(Vt, g_ws, w_bf, w_o, out);
}

// Round 6
// 398.601 us; speedup vs baseline: 1.5599x; 1.5599x over previous
//
#include <hip/hip_runtime.h>
#include <hip/hip_bf16.h>
#include <stdint.h>

#define S_DIM 512
#define R_DIM 384
#define CMSA 64
#define CZ 128
#define HH 8
#define CHID 32
#define HC 256
#define INF_V 1e8f
#define EPS_V 1e-5f

typedef __bf16 bf16x8 __attribute__((ext_vector_type(8)));
typedef float f32x4 __attribute__((ext_vector_type(4)));

__device__ __forceinline__ unsigned short f2bf(float f) {
  __hip_bfloat16 h = __float2bfloat16(f);
  return *reinterpret_cast<unsigned short*>(&h);
}
__device__ __forceinline__ float bf2f(unsigned short u) {
  __hip_bfloat16 h;
  *reinterpret_cast<unsigned short*>(&h) = u;
  return __bfloat162float(h);
}
__device__ __forceinline__ int4 pack8(const unsigned short* u) {
  int4 p;
  p.x = (int)u[0] | ((int)u[1] << 16);
  p.y = (int)u[2] | ((int)u[3] << 16);
  p.z = (int)u[4] | ((int)u[5] << 16);
  p.w = (int)u[6] | ((int)u[7] << 16);
  return p;
}

// 8-value simultaneous butterfly reduce over an 8-lane xor-group.
// Returns sum over the 8 lanes of s[cs7] (deposited so lane cs7 holds head cs7).
__device__ __forceinline__ float reduce8x(float* s, int cs7) {
  float t[4];
#pragma unroll
  for (int k = 0; k < 4; ++k) {
    float snd = (cs7 & 1) ? s[2 * k] : s[2 * k + 1];
    float rcv = __shfl_xor(snd, 1);
    t[k] = ((cs7 & 1) ? s[2 * k + 1] : s[2 * k]) + rcv;
  }
  float r[2];
#pragma unroll
  for (int k = 0; k < 2; ++k) {
    float snd = (cs7 & 2) ? t[2 * k] : t[2 * k + 1];
    float rcv = __shfl_xor(snd, 2);
    r[k] = ((cs7 & 2) ? t[2 * k + 1] : t[2 * k]) + rcv;
  }
  float snd = (cs7 & 4) ? r[0] : r[1];
  float rcv = __shfl_xor(snd, 4);
  return ((cs7 & 4) ? r[1] : r[0]) + rcv;
}

// ---------------------------------------------------------------------------
// K1 (rewritten): b[i,h,j] = LN(z)@w_b + INF*(mask-1), via the identity
//   b = rs*S_h - rs*mu*U_h + A_h,  S_h = sum_c z*lnw*wb, U=sum lnw*wb, A=sum lnb*wb
// 16 lanes/pair (4 pairs/wave); w_b held in VGPRs; zero LDS; grid-stride.
// ---------------------------------------------------------------------------
__global__ __launch_bounds__(256) void k_bias(
    const float* __restrict__ z, const float* __restrict__ z_mask,
    const float* __restrict__ lnw, const float* __restrict__ lnb,
    const float* __restrict__ w_b, float* __restrict__ b_out) {
  int tid = threadIdx.x, lane = tid & 63, wv = tid >> 6;
  int cs = lane & 15, ps = lane >> 4;   // pair-sub 0..3, chan-sub 0..15
  int cs7 = cs & 7;

  // my 8 channels: c = q*64 + cs*4 + e  (q=0..1, e=0..3)
  float4 wba[2][4], wbb[2][4], lnw4[2];
  float aU[8] = {0, 0, 0, 0, 0, 0, 0, 0};
  float aA[8] = {0, 0, 0, 0, 0, 0, 0, 0};
#pragma unroll
  for (int q = 0; q < 2; ++q) {
    int c0 = q * 64 + cs * 4;
    lnw4[q] = *reinterpret_cast<const float4*>(&lnw[c0]);
    float4 lnb4 = *reinterpret_cast<const float4*>(&lnb[c0]);
#pragma unroll
    for (int e = 0; e < 4; ++e) {
      wba[q][e] = *reinterpret_cast<const float4*>(&w_b[(size_t)(c0 + e) * HH]);
      wbb[q][e] = *reinterpret_cast<const float4*>(&w_b[(size_t)(c0 + e) * HH + 4]);
      float lw = reinterpret_cast<const float*>(&lnw4[q])[e];
      float lb = reinterpret_cast<const float*>(&lnb4)[e];
      aU[0] += lw * wba[q][e].x; aU[1] += lw * wba[q][e].y;
      aU[2] += lw * wba[q][e].z; aU[3] += lw * wba[q][e].w;
      aU[4] += lw * wbb[q][e].x; aU[5] += lw * wbb[q][e].y;
      aU[6] += lw * wbb[q][e].z; aU[7] += lw * wbb[q][e].w;
      aA[0] += lb * wba[q][e].x; aA[1] += lb * wba[q][e].y;
      aA[2] += lb * wba[q][e].z; aA[3] += lb * wba[q][e].w;
      aA[4] += lb * wbb[q][e].x; aA[5] += lb * wbb[q][e].y;
      aA[6] += lb * wbb[q][e].z; aA[7] += lb * wbb[q][e].w;
    }
  }
#pragma unroll
  for (int h = 0; h < 8; ++h) {
    aU[h] += __shfl_xor(aU[h], 8);
    aA[h] += __shfl_xor(aA[h], 8);
  }
  float U_l = reduce8x(aU, cs7);
  float A_l = reduce8x(aA, cs7);

  const int NTASK = (R_DIM * R_DIM) / 4;   // 36864 wave-tasks (4 pairs each)
  for (int task = blockIdx.x * 4 + wv; task < NTASK; task += gridDim.x * 4) {
    int g = task * 4 + ps;                 // this lane's pair
    const float* zp = z + (size_t)g * CZ;
    float4 zv[2];
    zv[0] = *reinterpret_cast<const float4*>(zp + cs * 4);
    zv[1] = *reinterpret_cast<const float4*>(zp + 64 + cs * 4);
    float sz = 0.f, sz2 = 0.f;
    float s[8] = {0, 0, 0, 0, 0, 0, 0, 0};
#pragma unroll
    for (int q = 0; q < 2; ++q)
#pragma unroll
      for (int e = 0; e < 4; ++e) {
        float x = reinterpret_cast<const float*>(&zv[q])[e];
        float lw = reinterpret_cast<const float*>(&lnw4[q])[e];
        sz += x; sz2 += x * x;
        float zn = x * lw;
        s[0] += zn * wba[q][e].x; s[1] += zn * wba[q][e].y;
        s[2] += zn * wba[q][e].z; s[3] += zn * wba[q][e].w;
        s[4] += zn * wbb[q][e].x; s[5] += zn * wbb[q][e].y;
        s[6] += zn * wbb[q][e].z; s[7] += zn * wbb[q][e].w;
      }
#pragma unroll
    for (int d = 1; d <= 8; d <<= 1) {
      sz += __shfl_xor(sz, d);
      sz2 += __shfl_xor(sz2, d);
    }
#pragma unroll
    for (int h = 0; h < 8; ++h) s[h] += __shfl_xor(s[h], 8);
    float S = reduce8x(s, cs7);
    float mu = sz * (1.f / CZ);
    float var = sz2 * (1.f / CZ) - mu * mu;
    float rs = rsqrtf(var + EPS_V);
    float b = rs * S + A_l - rs * mu * U_l + INF_V * (z_mask[g] - 1.f);
    if (cs < 8) {
      int i = g / R_DIM, j = g - i * R_DIM;
      b_out[((size_t)i * HH + cs) * R_DIM + j] = b;
    }
  }
}

// ---------------------------------------------------------------------------
// K2: softmax over j for each (i,h); write bf16 w_bf[h][i][j]
// ---------------------------------------------------------------------------
__global__ __launch_bounds__(128) void k_softmax(
    const float* __restrict__ b_in, unsigned short* __restrict__ w_bf) {
  int row = blockIdx.x;              // i*8 + h
  int i = row / HH, h = row - i * HH;
  const float* bp = b_in + (size_t)row * R_DIM;
  int t = threadIdx.x;
  float v[3];
  float mx = -INFINITY;
#pragma unroll
  for (int k = 0; k < 3; ++k) { v[k] = bp[t + 128 * k]; mx = fmaxf(mx, v[k]); }
  __shared__ float red[128];
  red[t] = mx; __syncthreads();
  for (int off = 64; off > 0; off >>= 1) {
    if (t < off) red[t] = fmaxf(red[t], red[t + off]);
    __syncthreads();
  }
  mx = red[0]; __syncthreads();
  float sum = 0.f;
#pragma unroll
  for (int k = 0; k < 3; ++k) { v[k] = __expf(v[k] - mx); sum += v[k]; }
  red[t] = sum; __syncthreads();
  for (int off = 64; off > 0; off >>= 1) {
    if (t < off) red[t] += red[t + off];
    __syncthreads();
  }
  float inv = 1.0f / red[0];
  unsigned short* wp = w_bf + ((size_t)h * R_DIM + i) * R_DIM;
#pragma unroll
  for (int k = 0; k < 3; ++k) wp[t + 128 * k] = f2bf(v[k] * inv);
}

// ---------------------------------------------------------------------------
// K3 (MFMA): v = (LN(m)@w_v)*mask -> Vt[s][hc][j] bf16 (LDS-transposed store)
//            g = sigmoid(LN(m)@w_g) -> g_ws[s][res][hc] bf16 (direct store)
// ---------------------------------------------------------------------------
__global__ __launch_bounds__(512) void k_vg(
    const float* __restrict__ m, const float* __restrict__ msa_mask,
    const float* __restrict__ lnw, const float* __restrict__ lnb,
    const float* __restrict__ w_v, const float* __restrict__ w_g,
    unsigned short* __restrict__ Vt, unsigned short* __restrict__ g_ws) {
  extern __shared__ char lds[];
  const int A_OFF = 0;         // 16384
  const int WV_OFF = 16384;    // 32768
  const int WG_OFF = 49152;    // 32768
  const int T_OFF = 81920;     // 256*272 = 69632
  const int M_OFF = 151552;    // 512
  int tid = threadIdx.x, l = tid & 63, wv = tid >> 6;
  int b = blockIdx.x;
  int s = b / 3;
  int res0 = (b % 3) * 128;
  size_t row0 = (size_t)s * R_DIM + res0;

  if (tid < 128) *reinterpret_cast<float*>(&lds[M_OFF + tid * 4]) = msa_mask[row0 + tid];

  // stage w_v^T, w_g^T as bf16 [hc][cm], XOR-swizzled (8 slots/row)
  for (int it = 0; it < 4; ++it) {
    int G = it * 512 + tid;
    int hcr = G >> 3, slot = G & 7;
    unsigned short uv[8], ug[8];
#pragma unroll
    for (int e = 0; e < 8; ++e) {
      uv[e] = f2bf(w_v[(size_t)(slot * 8 + e) * HC + hcr]);
      ug[e] = f2bf(w_g[(size_t)(slot * 8 + e) * HC + hcr]);
    }
    int swz = hcr * 128 + ((slot ^ (hcr & 7)) << 4);
    *reinterpret_cast<int4*>(&lds[WV_OFF + swz]) = pack8(uv);
    *reinterpret_cast<int4*>(&lds[WG_OFF + swz]) = pack8(ug);
  }

  // LN(m) -> A-lds bf16 swizzled
  float lw = lnw[l], lbv = lnb[l];
  for (int q = 0; q < 16; ++q) {
    int r = wv * 16 + q;
    float x = m[(row0 + r) * CMSA + l];
    float sm = x, s2 = x * x;
#pragma unroll
    for (int d = 1; d < 64; d <<= 1) { sm += __shfl_xor(sm, d); s2 += __shfl_xor(s2, d); }
    float mu = sm * (1.f / 64.f);
    float var = s2 * (1.f / 64.f) - mu * mu;
    float nv = (x - mu) * rsqrtf(var + EPS_V) * lw + lbv;
    *reinterpret_cast<unsigned short*>(
        &lds[A_OFF + r * 128 + (((l >> 3) ^ (r & 7)) << 4) + (l & 7) * 2]) = f2bf(nv);
  }
  __syncthreads();

  f32x4 zz = {0.f, 0.f, 0.f, 0.f};
  // ---- v phase: D[res][hc] = LN @ w_v ----
  f32x4 vacc[2][8];
#pragma unroll
  for (int a = 0; a < 2; ++a)
#pragma unroll
    for (int n = 0; n < 8; ++n) vacc[a][n] = zz;
#pragma unroll
  for (int kc = 0; kc < 2; ++kc) {
    bf16x8 af[2], bfv[8];
#pragma unroll
    for (int mf = 0; mf < 2; ++mf) {
      int row = ((wv & 3) * 2 + mf) * 16 + (l & 15);
      af[mf] = *reinterpret_cast<const bf16x8*>(
          &lds[A_OFF + row * 128 + (((kc * 4 + (l >> 4)) ^ (row & 7)) << 4)]);
    }
#pragma unroll
    for (int nf = 0; nf < 8; ++nf) {
      int row = ((wv >> 2) * 8 + nf) * 16 + (l & 15);
      bfv[nf] = *reinterpret_cast<const bf16x8*>(
          &lds[WV_OFF + row * 128 + (((kc * 4 + (l >> 4)) ^ (row & 7)) << 4)]);
    }
#pragma unroll
    for (int mf = 0; mf < 2; ++mf)
#pragma unroll
      for (int nf = 0; nf < 8; ++nf)
        vacc[mf][nf] = __builtin_amdgcn_mfma_f32_16x16x32_bf16(af[mf], bfv[nf], vacc[mf][nf], 0, 0, 0);
  }
  // epilogue v: mask, bf16, T[hc][res] (row stride 272B)
#pragma unroll
  for (int mf = 0; mf < 2; ++mf) {
    int resb = ((wv & 3) * 2 + mf) * 16 + (l >> 4) * 4;
    float4 mk = *reinterpret_cast<const float4*>(&lds[M_OFF + resb * 4]);
#pragma unroll
    for (int nf = 0; nf < 8; ++nf) {
      int hc = ((wv >> 2) * 8 + nf) * 16 + (l & 15);
      ushort4 o;
      o.x = f2bf(vacc[mf][nf][0] * mk.x);
      o.y = f2bf(vacc[mf][nf][1] * mk.y);
      o.z = f2bf(vacc[mf][nf][2] * mk.z);
      o.w = f2bf(vacc[mf][nf][3] * mk.w);
      *reinterpret_cast<ushort4*>(&lds[T_OFF + hc * 272 + resb * 2]) = o;
    }
  }
  __syncthreads();
  // coalesced Vt store: Vt[(s*256+hc)*384 + res0 + ...]
  for (int it = 0; it < 8; ++it) {
    int G = it * 512 + tid;
    int hc = G >> 4, gi = G & 15;
    int4 d = *reinterpret_cast<const int4*>(&lds[T_OFF + hc * 272 + gi * 16]);
    *reinterpret_cast<int4*>(&Vt[((size_t)s * HC + hc) * R_DIM + res0 + gi * 8]) = d;
  }

  // ---- g phase: sigmoid(LN @ w_g), direct store g_ws[s][res][hc] ----
  f32x4 gacc[2][8];
#pragma unroll
  for (int a = 0; a < 2; ++a)
#pragma unroll
    for (int n = 0; n < 8; ++n) gacc[a][n] = zz;
#pragma unroll
  for (int kc = 0; kc < 2; ++kc) {
    bf16x8 af[2], bfg[8];
#pragma unroll
    for (int mf = 0; mf < 2; ++mf) {
      int row = ((wv & 3) * 2 + mf) * 16 + (l & 15);
      af[mf] = *reinterpret_cast<const bf16x8*>(
          &lds[A_OFF + row * 128 + (((kc * 4 + (l >> 4)) ^ (row & 7)) << 4)]);
    }
#pragma unroll
    for (int nf = 0; nf < 8; ++nf) {
      int row = ((wv >> 2) * 8 + nf) * 16 + (l & 15);
      bfg[nf] = *reinterpret_cast<const bf16x8*>(
          &lds[WG_OFF + row * 128 + (((kc * 4 + (l >> 4)) ^ (row & 7)) << 4)]);
    }
#pragma unroll
    for (int mf = 0; mf < 2; ++mf)
#pragma unroll
      for (int nf = 0; nf < 8; ++nf)
        gacc[mf][nf] = __builtin_amdgcn_mfma_f32_16x16x32_bf16(af[mf], bfg[nf], gacc[mf][nf], 0, 0, 0);
  }
#pragma unroll
  for (int mf = 0; mf < 2; ++mf)
#pragma unroll
    for (int nf = 0; nf < 8; ++nf) {
      int hc = ((wv >> 2) * 8 + nf) * 16 + (l & 15);
#pragma unroll
      for (int reg = 0; reg < 4; ++reg) {
        int res = ((wv & 3) * 2 + mf) * 16 + (l >> 4) * 4 + reg;
        float sg = 1.f / (1.f + __expf(-gacc[mf][nf][reg]));
        g_ws[(row0 + res) * HC + hc] = f2bf(sg);  // 16-lane 32B runs
      }
    }
}

// ---------------------------------------------------------------------------
// K4 (MFMA, fused): per block (8 s, 96 i), loop h:
//   einsum o^T[(sl,c)][i] = Vt-tile @ w_bf-tile  (dbuf reg-staged LDS, swz)
//   gate with g_ws, P-lds[768 rows (sl,i)][32 c]
//   proj MFMA: out-acc += P @ w_o^T[h-slice]  (acc in regs across heads)
// ---------------------------------------------------------------------------
__global__ __launch_bounds__(512) void k_wavg(
    const unsigned short* __restrict__ Vt, const unsigned short* __restrict__ g_ws,
    const unsigned short* __restrict__ w_bf, const float* __restrict__ w_o,
    float* __restrict__ out) {
  extern __shared__ char lds[];
  const int A_OFF = 0;       // 2 x 16384
  const int B_OFF = 32768;   // 2 x 6144
  const int P_OFF = 45056;   // 49152
  const int W_OFF = 94208;   // 32768
  int tid = threadIdx.x, l = tid & 63, wv = tid >> 6;
  int bs = blockIdx.x >> 2, bi = blockIdx.x & 3;
  int s0 = bs * 8, i0 = bi * 96;

  // stage w_o^T bf16 [64 l][256 hc], 32 slots/row, XOR (lrow&7)
  for (int it = 0; it < 4; ++it) {
    int G = it * 512 + tid;
    int lrow = G >> 5, slot = G & 31;
    unsigned short u[8];
#pragma unroll
    for (int e = 0; e < 8; ++e) u[e] = f2bf(w_o[(size_t)(slot * 8 + e) * CMSA + lrow]);
    *reinterpret_cast<int4*>(&lds[W_OFF + lrow * 512 + ((slot ^ (lrow & 7)) << 4)]) = pack8(u);
  }

  // staging constants (A: 1024 granules = 2/thread; B: 384 granules)
  int slotg = tid & 3;
  int rA0 = tid >> 2, rA1 = 128 + (tid >> 2);
  size_t vtb0 = ((size_t)(s0 + (rA0 >> 5)) * HC + (rA0 & 31)) * R_DIM + slotg * 8;
  size_t vtb1 = ((size_t)(s0 + (rA1 >> 5)) * HC + (rA1 & 31)) * R_DIM + slotg * 8;
  int ldsA0 = rA0 * 64 + ((slotg ^ (rA0 & 3)) << 4);
  int ldsA1 = rA1 * 64 + ((slotg ^ (rA1 & 3)) << 4);
  int rB = tid >> 2;
  size_t wbase = (size_t)(i0 + rB) * R_DIM + slotg * 8;
  int ldsB = rB * 64 + ((slotg ^ (rB & 3)) << 4);

  int aoff[4], boff[3], poff[6];
#pragma unroll
  for (int mf = 0; mf < 4; ++mf) {
    int row = ((wv & 3) * 4 + mf) * 16 + (l & 15);
    aoff[mf] = row * 64 + (((l >> 4) ^ (row & 3)) << 4);
  }
#pragma unroll
  for (int nf = 0; nf < 3; ++nf) {
    int row = ((wv >> 2) * 3 + nf) * 16 + (l & 15);
    boff[nf] = row * 64 + (((l >> 4) ^ (row & 3)) << 4);
  }
#pragma unroll
  for (int mf = 0; mf < 6; ++mf) {
    int row = (wv * 6 + mf) * 16 + (l & 15);
    poff[mf] = row * 64 + (((l >> 4) ^ (row & 3)) << 4);
  }

  f32x4 zz = {0.f, 0.f, 0.f, 0.f};
  f32x4 pacc[6][4];
#pragma unroll
  for (int a = 0; a < 6; ++a)
#pragma unroll
    for (int n = 0; n < 4; ++n) pacc[a][n] = zz;

  for (int h = 0; h < 8; ++h) {
    const unsigned short* VtA = Vt + (size_t)h * 32 * R_DIM;
    const unsigned short* WB = w_bf + (size_t)h * R_DIM * R_DIM;
    f32x4 acc[4][3];
#pragma unroll
    for (int a = 0; a < 4; ++a)
#pragma unroll
      for (int n = 0; n < 3; ++n) acc[a][n] = zz;

    { // prologue: stage k-step 0 into buf 0
      int4 va0 = *reinterpret_cast<const int4*>(VtA + vtb0);
      int4 va1 = *reinterpret_cast<const int4*>(VtA + vtb1);
      int4 vb;
      if (tid < 384) vb = *reinterpret_cast<const int4*>(WB + wbase);
      *reinterpret_cast<int4*>(&lds[A_OFF + ldsA0]) = va0;
      *reinterpret_cast<int4*>(&lds[A_OFF + ldsA1]) = va1;
      if (tid < 384) *reinterpret_cast<int4*>(&lds[B_OFF + ldsB]) = vb;
    }
    __syncthreads();

    for (int t = 0; t < 12; ++t) {
      int cur = t & 1;
      int4 va0, va1, vb;
      if (t < 11) {
        int j0n = (t + 1) * 32;
        va0 = *reinterpret_cast<const int4*>(VtA + vtb0 + j0n);
        va1 = *reinterpret_cast<const int4*>(VtA + vtb1 + j0n);
        if (tid < 384) vb = *reinterpret_cast<const int4*>(WB + wbase + j0n);
      }
      const char* ab = &lds[A_OFF + cur * 16384];
      const char* bb = &lds[B_OFF + cur * 6144];
      bf16x8 af[4], bfr[3];
#pragma unroll
      for (int mf = 0; mf < 4; ++mf) af[mf] = *reinterpret_cast<const bf16x8*>(ab + aoff[mf]);
#pragma unroll
      for (int nf = 0; nf < 3; ++nf) bfr[nf] = *reinterpret_cast<const bf16x8*>(bb + boff[nf]);
#pragma unroll
      for (int mf = 0; mf < 4; ++mf)
#pragma unroll
        for (int nf = 0; nf < 3; ++nf)
          acc[mf][nf] = __builtin_amdgcn_mfma_f32_16x16x32_bf16(af[mf], bfr[nf], acc[mf][nf], 0, 0, 0);
      if (t < 11) {
        int nxt = cur ^ 1;
        *reinterpret_cast<int4*>(&lds[A_OFF + nxt * 16384 + ldsA0]) = va0;
        *reinterpret_cast<int4*>(&lds[A_OFF + nxt * 16384 + ldsA1]) = va1;
        if (tid < 384) *reinterpret_cast<int4*>(&lds[B_OFF + nxt * 6144 + ldsB]) = vb;
      }
      __syncthreads();
    }

    // gate + P write: P[prow = sl*96+il][c], 64B rows, XOR (prow&3)
#pragma unroll
    for (int mf = 0; mf < 4; ++mf) {
      int MT = (wv & 3) * 4 + mf;
      int sl = MT >> 1;
      int c0 = (MT & 1) * 16 + (l >> 4) * 4;
#pragma unroll
      for (int nf = 0; nf < 3; ++nf) {
        int il = ((wv >> 2) * 3 + nf) * 16 + (l & 15);
        size_t gidx = ((size_t)(s0 + sl) * R_DIM + i0 + il) * HC + h * 32 + c0;
        ushort4 g4 = *reinterpret_cast<const ushort4*>(g_ws + gidx);
        int prow = sl * 96 + il;
        ushort4 og;
        og.x = f2bf(acc[mf][nf][0] * bf2f(g4.x));
        og.y = f2bf(acc[mf][nf][1] * bf2f(g4.y));
        og.z = f2bf(acc[mf][nf][2] * bf2f(g4.z));
        og.w = f2bf(acc[mf][nf][3] * bf2f(g4.w));
        *reinterpret_cast<ushort4*>(
            &lds[P_OFF + prow * 64 + (((c0 >> 3) ^ (prow & 3)) << 4) + (c0 & 7) * 2]) = og;
      }
    }
    __syncthreads();

    // projection: pacc += P @ w_oT[h-slice]
    {
      bf16x8 pa[6], bw[4];
#pragma unroll
      for (int nt = 0; nt < 4; ++nt) {
        int lrow = nt * 16 + (l & 15);
        bw[nt] = *reinterpret_cast<const bf16x8*>(
            &lds[W_OFF + lrow * 512 + (((h * 4 + (l >> 4)) ^ (lrow & 7)) << 4)]);
      }
#pragma unroll
      for (int mf = 0; mf < 6; ++mf) pa[mf] = *reinterpret_cast<const bf16x8*>(&lds[P_OFF + poff[mf]]);
#pragma unroll
      for (int mf = 0; mf < 6; ++mf)
#pragma unroll
        for (int nt = 0; nt < 4; ++nt)
          pacc[mf][nt] = __builtin_amdgcn_mfma_f32_16x16x32_bf16(pa[mf], bw[nt], pacc[mf][nt], 0, 0, 0);
    }
    __syncthreads();
  }

  // final store: out[(s0+sl)*384 + i0+il][l-col] fp32, 64B runs
#pragma unroll
  for (int mf = 0; mf < 6; ++mf) {
#pragma unroll
    for (int reg = 0; reg < 4; ++reg) {
      int prow = (wv * 6 + mf) * 16 + (l >> 4) * 4 + reg;
      int sl = prow / 96;
      int il = prow - sl * 96;
      size_t orow = (size_t)(s0 + sl) * R_DIM + i0 + il;
#pragma unroll
      for (int nt = 0; nt < 4; ++nt)
        out[orow * CMSA + nt * 16 + (l & 15)] = pacc[mf][nt][reg];
    }
  }
}

// ---------------------------------------------------------------------------
extern "C" void kernel_launch(void* const* d_in, const int* in_sizes, int n_in,
                              void* d_out, int out_size, void* d_ws, size_t ws_size,
                              hipStream_t stream) {
  (void)in_sizes; (void)n_in; (void)out_size; (void)ws_size;
  const float* m        = (const float*)d_in[0];
  const float* z        = (const float*)d_in[1];
  const float* msa_mask = (const float*)d_in[2];
  const float* z_mask   = (const float*)d_in[3];
  const float* ln_m_w   = (const float*)d_in[4];
  const float* ln_m_b   = (const float*)d_in[5];
  const float* ln_z_w   = (const float*)d_in[6];
  const float* ln_z_b   = (const float*)d_in[7];
  const float* w_v      = (const float*)d_in[8];
  const float* w_g      = (const float*)d_in[9];
  const float* w_b      = (const float*)d_in[10];
  const float* w_o      = (const float*)d_in[11];
  float* out = (float*)d_out;

  char* ws = (char*)d_ws;
  unsigned short* Vt   = (unsigned short*)ws;                     // 100,663,296 B
  unsigned short* g_ws = (unsigned short*)(ws + 100663296ull);    // 100,663,296 B
  float*          b_ws = (float*)(ws + 201326592ull);             //   4,718,592 B
  unsigned short* w_bf = (unsigned short*)(ws + 206045184ull);    //   2,359,296 B

  k_bias<<<dim3(2304), dim3(256), 0, stream>>>(
      z, z_mask, ln_z_w, ln_z_b, w_b, b_ws);
  k_softmax<<<dim3(R_DIM * HH), dim3(128), 0, stream>>>(b_ws, w_bf);
  k_vg<<<dim3(S_DIM * R_DIM / 128), dim3(512), 152064, stream>>>(
      m, msa_mask, ln_m_w, ln_m_b, w_v, w_g, Vt, g_ws);
  k_wavg<<<dim3(256), dim3(512), 126976, stream>>>(Vt, g_ws, w_bf, w_o, out);
}

// Round 8
// 346.978 us; speedup vs baseline: 1.7919x; 1.1488x over previous
//
#include <hip/hip_runtime.h>
#include <hip/hip_bf16.h>
#include <stdint.h>

#define S_DIM 512
#define R_DIM 384
#define CMSA 64
#define CZ 128
#define HH 8
#define CHID 32
#define HC 256
#define INF_V 1e8f
#define EPS_V 1e-5f

typedef __bf16 bf16x8 __attribute__((ext_vector_type(8)));
typedef float f32x4 __attribute__((ext_vector_type(4)));

__device__ __forceinline__ unsigned short f2bf(float f) {
  __hip_bfloat16 h = __float2bfloat16(f);
  return *reinterpret_cast<unsigned short*>(&h);
}
__device__ __forceinline__ float bf2f(unsigned short u) {
  __hip_bfloat16 h;
  *reinterpret_cast<unsigned short*>(&h) = u;
  return __bfloat162float(h);
}
__device__ __forceinline__ int4 pack8(const unsigned short* u) {
  int4 p;
  p.x = (int)u[0] | ((int)u[1] << 16);
  p.y = (int)u[2] | ((int)u[3] << 16);
  p.z = (int)u[4] | ((int)u[5] << 16);
  p.w = (int)u[6] | ((int)u[7] << 16);
  return p;
}

// 8-value simultaneous butterfly reduce over an 8-lane xor-group.
__device__ __forceinline__ float reduce8x(float* s, int cs7) {
  float t[4];
#pragma unroll
  for (int k = 0; k < 4; ++k) {
    float snd = (cs7 & 1) ? s[2 * k] : s[2 * k + 1];
    float rcv = __shfl_xor(snd, 1);
    t[k] = ((cs7 & 1) ? s[2 * k + 1] : s[2 * k]) + rcv;
  }
  float r[2];
#pragma unroll
  for (int k = 0; k < 2; ++k) {
    float snd = (cs7 & 2) ? t[2 * k] : t[2 * k + 1];
    float rcv = __shfl_xor(snd, 2);
    r[k] = ((cs7 & 2) ? t[2 * k + 1] : t[2 * k]) + rcv;
  }
  float snd = (cs7 & 4) ? r[0] : r[1];
  float rcv = __shfl_xor(snd, 4);
  return ((cs7 & 4) ? r[1] : r[0]) + rcv;
}

// ---------------------------------------------------------------------------
// K1: b[i,h,j] = LN(z)@w_b + INF*(mask-1)  (validated R6: off the hot list)
// ---------------------------------------------------------------------------
__global__ __launch_bounds__(256) void k_bias(
    const float* __restrict__ z, const float* __restrict__ z_mask,
    const float* __restrict__ lnw, const float* __restrict__ lnb,
    const float* __restrict__ w_b, float* __restrict__ b_out) {
  int tid = threadIdx.x, lane = tid & 63, wv = tid >> 6;
  int cs = lane & 15, ps = lane >> 4;
  int cs7 = cs & 7;

  float4 wba[2][4], wbb[2][4], lnw4[2];
  float aU[8] = {0, 0, 0, 0, 0, 0, 0, 0};
  float aA[8] = {0, 0, 0, 0, 0, 0, 0, 0};
#pragma unroll
  for (int q = 0; q < 2; ++q) {
    int c0 = q * 64 + cs * 4;
    lnw4[q] = *reinterpret_cast<const float4*>(&lnw[c0]);
    float4 lnb4 = *reinterpret_cast<const float4*>(&lnb[c0]);
#pragma unroll
    for (int e = 0; e < 4; ++e) {
      wba[q][e] = *reinterpret_cast<const float4*>(&w_b[(size_t)(c0 + e) * HH]);
      wbb[q][e] = *reinterpret_cast<const float4*>(&w_b[(size_t)(c0 + e) * HH + 4]);
      float lw = reinterpret_cast<const float*>(&lnw4[q])[e];
      float lb = reinterpret_cast<const float*>(&lnb4)[e];
      aU[0] += lw * wba[q][e].x; aU[1] += lw * wba[q][e].y;
      aU[2] += lw * wba[q][e].z; aU[3] += lw * wba[q][e].w;
      aU[4] += lw * wbb[q][e].x; aU[5] += lw * wbb[q][e].y;
      aU[6] += lw * wbb[q][e].z; aU[7] += lw * wbb[q][e].w;
      aA[0] += lb * wba[q][e].x; aA[1] += lb * wba[q][e].y;
      aA[2] += lb * wba[q][e].z; aA[3] += lb * wba[q][e].w;
      aA[4] += lb * wbb[q][e].x; aA[5] += lb * wbb[q][e].y;
      aA[6] += lb * wbb[q][e].z; aA[7] += lb * wbb[q][e].w;
    }
  }
#pragma unroll
  for (int h = 0; h < 8; ++h) {
    aU[h] += __shfl_xor(aU[h], 8);
    aA[h] += __shfl_xor(aA[h], 8);
  }
  float U_l = reduce8x(aU, cs7);
  float A_l = reduce8x(aA, cs7);

  const int NTASK = (R_DIM * R_DIM) / 4;
  for (int task = blockIdx.x * 4 + wv; task < NTASK; task += gridDim.x * 4) {
    int g = task * 4 + ps;
    const float* zp = z + (size_t)g * CZ;
    float4 zv[2];
    zv[0] = *reinterpret_cast<const float4*>(zp + cs * 4);
    zv[1] = *reinterpret_cast<const float4*>(zp + 64 + cs * 4);
    float sz = 0.f, sz2 = 0.f;
    float s[8] = {0, 0, 0, 0, 0, 0, 0, 0};
#pragma unroll
    for (int q = 0; q < 2; ++q)
#pragma unroll
      for (int e = 0; e < 4; ++e) {
        float x = reinterpret_cast<const float*>(&zv[q])[e];
        float lw = reinterpret_cast<const float*>(&lnw4[q])[e];
        sz += x; sz2 += x * x;
        float zn = x * lw;
        s[0] += zn * wba[q][e].x; s[1] += zn * wba[q][e].y;
        s[2] += zn * wba[q][e].z; s[3] += zn * wba[q][e].w;
        s[4] += zn * wbb[q][e].x; s[5] += zn * wbb[q][e].y;
        s[6] += zn * wbb[q][e].z; s[7] += zn * wbb[q][e].w;
      }
#pragma unroll
    for (int d = 1; d <= 8; d <<= 1) {
      sz += __shfl_xor(sz, d);
      sz2 += __shfl_xor(sz2, d);
    }
#pragma unroll
    for (int h = 0; h < 8; ++h) s[h] += __shfl_xor(s[h], 8);
    float S = reduce8x(s, cs7);
    float mu = sz * (1.f / CZ);
    float var = sz2 * (1.f / CZ) - mu * mu;
    float rs = rsqrtf(var + EPS_V);
    float b = rs * S + A_l - rs * mu * U_l + INF_V * (z_mask[g] - 1.f);
    if (cs < 8) {
      int i = g / R_DIM, j = g - i * R_DIM;
      b_out[((size_t)i * HH + cs) * R_DIM + j] = b;
    }
  }
}

// ---------------------------------------------------------------------------
// K2: softmax over j; write bf16 w_bf[h][i][j]
// ---------------------------------------------------------------------------
__global__ __launch_bounds__(128) void k_softmax(
    const float* __restrict__ b_in, unsigned short* __restrict__ w_bf) {
  int row = blockIdx.x;
  int i = row / HH, h = row - i * HH;
  const float* bp = b_in + (size_t)row * R_DIM;
  int t = threadIdx.x;
  float v[3];
  float mx = -INFINITY;
#pragma unroll
  for (int k = 0; k < 3; ++k) { v[k] = bp[t + 128 * k]; mx = fmaxf(mx, v[k]); }
  __shared__ float red[128];
  red[t] = mx; __syncthreads();
  for (int off = 64; off > 0; off >>= 1) {
    if (t < off) red[t] = fmaxf(red[t], red[t + off]);
    __syncthreads();
  }
  mx = red[0]; __syncthreads();
  float sum = 0.f;
#pragma unroll
  for (int k = 0; k < 3; ++k) { v[k] = __expf(v[k] - mx); sum += v[k]; }
  red[t] = sum; __syncthreads();
  for (int off = 64; off > 0; off >>= 1) {
    if (t < off) red[t] += red[t + off];
    __syncthreads();
  }
  float inv = 1.0f / red[0];
  unsigned short* wp = w_bf + ((size_t)h * R_DIM + i) * R_DIM;
#pragma unroll
  for (int k = 0; k < 3; ++k) wp[t + 128 * k] = f2bf(v[k] * inv);
}

// ---------------------------------------------------------------------------
// K-PREP: convert w_v/w_g/w_o once into bf16 pre-swizzled LDS images.
// Image layouts match the consumers' ds_read swizzle exactly (identity copy).
// ---------------------------------------------------------------------------
__global__ __launch_bounds__(256) void k_prep(
    const float* __restrict__ w_v, const float* __restrict__ w_g,
    const float* __restrict__ w_o, unsigned short* __restrict__ wv_img,
    unsigned short* __restrict__ wg_img, unsigned short* __restrict__ wo_img) {
  int gid = blockIdx.x * 256 + threadIdx.x;   // 0..6143
  int mtx = gid >> 11, idx = gid & 2047;
  unsigned short u[8];
  if (mtx < 2) {
    const float* w = mtx ? w_g : w_v;
    unsigned short* img = mtx ? wg_img : wv_img;
    int hcr = idx >> 3, slot = idx & 7;
#pragma unroll
    for (int e = 0; e < 8; ++e) u[e] = f2bf(w[(size_t)(slot * 8 + e) * HC + hcr]);
    *reinterpret_cast<int4*>(&img[hcr * 64 + ((slot ^ (hcr & 7)) << 3)]) = pack8(u);
  } else {
    int lrow = idx >> 5, slot = idx & 31;
#pragma unroll
    for (int e = 0; e < 8; ++e) u[e] = f2bf(w_o[(size_t)(slot * 8 + e) * CMSA + lrow]);
    *reinterpret_cast<int4*>(&wo_img[lrow * 256 + ((slot ^ (lrow & 7)) << 3)]) = pack8(u);
  }
}

// ---------------------------------------------------------------------------
// K3 (rewritten): LDS 48.5KB (A 16K + W 32K reused + mask), ~3 blocks/CU.
//  v phase: D[hc][res] = mfma(W_frag(row=hc), LN_frag(col=res)) -> direct
//           32B-run stores to Vt[s][hc][res] (no transpose buffer).
//  g phase: D[res][hc] = mfma(LN_frag(row=res), W_frag(col=hc)) (validated
//           tiling) -> g_ws[s][res][hc].
//  LN: 4 lanes/row, 2-shuffle reduce, float4 loads.
// ---------------------------------------------------------------------------
__global__ __launch_bounds__(512, 4) void k_vg(
    const float* __restrict__ m, const float* __restrict__ msa_mask,
    const float* __restrict__ lnw, const float* __restrict__ lnb,
    const unsigned short* __restrict__ wv_img,
    const unsigned short* __restrict__ wg_img,
    unsigned short* __restrict__ Vt, unsigned short* __restrict__ g_ws) {
  extern __shared__ char lds[];
  const int A_OFF = 0;       // 16384: LN tile [128 res][64 cm] bf16 swz
  const int W_OFF = 16384;   // 32768: weight tile [256][64] bf16 swz
  const int M_OFF = 49152;   // 512:   mask f32
  int tid = threadIdx.x, l = tid & 63, wv = tid >> 6;
  int b = blockIdx.x;
  int s = b / 3;
  int res0 = (b % 3) * 128;
  size_t row0 = (size_t)s * R_DIM + res0;

  if (tid < 128) *reinterpret_cast<float*>(&lds[M_OFF + tid * 4]) = msa_mask[row0 + tid];

  // stage w_v image: coalesced identity copy (32KB)
  {
    const int4* src = reinterpret_cast<const int4*>(wv_img);
    int4* dst = reinterpret_cast<int4*>(&lds[W_OFF]);
#pragma unroll
    for (int p = 0; p < 4; ++p) dst[p * 512 + tid] = src[p * 512 + tid];
  }

  // LN: 4 lanes per row (row = tid>>2, quarter q = tid&3 -> channels q*16..+15)
  {
    int row = tid >> 2, q = tid & 3;
    const float* mp = m + (row0 + row) * CMSA + q * 16;
    float4 x0 = *reinterpret_cast<const float4*>(mp);
    float4 x1 = *reinterpret_cast<const float4*>(mp + 4);
    float4 x2 = *reinterpret_cast<const float4*>(mp + 8);
    float4 x3 = *reinterpret_cast<const float4*>(mp + 12);
    float xs[16] = {x0.x, x0.y, x0.z, x0.w, x1.x, x1.y, x1.z, x1.w,
                    x2.x, x2.y, x2.z, x2.w, x3.x, x3.y, x3.z, x3.w};
    float sm = 0.f, s2 = 0.f;
#pragma unroll
    for (int e = 0; e < 16; ++e) { sm += xs[e]; s2 += xs[e] * xs[e]; }
    sm += __shfl_xor(sm, 1); s2 += __shfl_xor(s2, 1);
    sm += __shfl_xor(sm, 2); s2 += __shfl_xor(s2, 2);
    float mu = sm * (1.f / 64.f);
    float var = s2 * (1.f / 64.f) - mu * mu;
    float rs = rsqrtf(var + EPS_V);
    const float* lwp = lnw + q * 16;
    const float* lbp = lnb + q * 16;
    unsigned short u[16];
#pragma unroll
    for (int e = 0; e < 16; ++e)
      u[e] = f2bf((xs[e] - mu) * rs * lwp[e] + lbp[e]);
    int base = A_OFF + row * 128;
    *reinterpret_cast<int4*>(&lds[base + (((2 * q) ^ (row & 7)) << 4)]) = pack8(u);
    *reinterpret_cast<int4*>(&lds[base + (((2 * q + 1) ^ (row & 7)) << 4)]) = pack8(u + 8);
  }
  __syncthreads();

  f32x4 zz = {0.f, 0.f, 0.f, 0.f};

  // ---- v phase: wave covers hc in [wv*32, wv*32+32), all 128 res ----
  {
    f32x4 vacc[2][8];
#pragma unroll
    for (int a = 0; a < 2; ++a)
#pragma unroll
      for (int n = 0; n < 8; ++n) vacc[a][n] = zz;
#pragma unroll
    for (int kc = 0; kc < 2; ++kc) {
      bf16x8 aw[2];
#pragma unroll
      for (int mfa = 0; mfa < 2; ++mfa) {
        int row = wv * 32 + mfa * 16 + (l & 15);
        aw[mfa] = *reinterpret_cast<const bf16x8*>(
            &lds[W_OFF + row * 128 + (((kc * 4 + (l >> 4)) ^ (row & 7)) << 4)]);
      }
#pragma unroll
      for (int nh = 0; nh < 2; ++nh) {
        bf16x8 bl[4];
#pragma unroll
        for (int nf = 0; nf < 4; ++nf) {
          int res = (nh * 4 + nf) * 16 + (l & 15);
          bl[nf] = *reinterpret_cast<const bf16x8*>(
              &lds[A_OFF + res * 128 + (((kc * 4 + (l >> 4)) ^ (res & 7)) << 4)]);
        }
#pragma unroll
        for (int mfa = 0; mfa < 2; ++mfa)
#pragma unroll
          for (int nf = 0; nf < 4; ++nf)
            vacc[mfa][nh * 4 + nf] =
                __builtin_amdgcn_mfma_f32_16x16x32_bf16(aw[mfa], bl[nf], vacc[mfa][nh * 4 + nf], 0, 0, 0);
      }
    }
    // store: col=lane&15 -> res (32B runs), row=(l>>4)*4+reg -> hc
    float mk[8];
#pragma unroll
    for (int nf = 0; nf < 8; ++nf)
      mk[nf] = *reinterpret_cast<const float*>(&lds[M_OFF + (nf * 16 + (l & 15)) * 4]);
#pragma unroll
    for (int mfa = 0; mfa < 2; ++mfa)
#pragma unroll
      for (int nf = 0; nf < 8; ++nf) {
#pragma unroll
        for (int reg = 0; reg < 4; ++reg) {
          int hc = wv * 32 + mfa * 16 + (l >> 4) * 4 + reg;
          Vt[((size_t)s * HC + hc) * R_DIM + res0 + nf * 16 + (l & 15)] =
              f2bf(vacc[mfa][nf][reg] * mk[nf]);
        }
      }
  }
  __syncthreads();

  // stage w_g image over the same W buffer
  {
    const int4* src = reinterpret_cast<const int4*>(wg_img);
    int4* dst = reinterpret_cast<int4*>(&lds[W_OFF]);
#pragma unroll
    for (int p = 0; p < 4; ++p) dst[p * 512 + tid] = src[p * 512 + tid];
  }
  __syncthreads();

  // ---- g phase: wave covers res in [(wv&3)*32, +32), hc in [(wv>>2)*128, +128) ----
  {
    int resb = (wv & 3) * 32, hcb = (wv >> 2) * 128;
    f32x4 gacc[2][8];
#pragma unroll
    for (int a = 0; a < 2; ++a)
#pragma unroll
      for (int n = 0; n < 8; ++n) gacc[a][n] = zz;
#pragma unroll
    for (int kc = 0; kc < 2; ++kc) {
      bf16x8 al[2];
#pragma unroll
      for (int mfa = 0; mfa < 2; ++mfa) {
        int row = resb + mfa * 16 + (l & 15);
        al[mfa] = *reinterpret_cast<const bf16x8*>(
            &lds[A_OFF + row * 128 + (((kc * 4 + (l >> 4)) ^ (row & 7)) << 4)]);
      }
#pragma unroll
      for (int nh = 0; nh < 2; ++nh) {
        bf16x8 bw[4];
#pragma unroll
        for (int nf = 0; nf < 4; ++nf) {
          int col = hcb + (nh * 4 + nf) * 16 + (l & 15);
          bw[nf] = *reinterpret_cast<const bf16x8*>(
              &lds[W_OFF + col * 128 + (((kc * 4 + (l >> 4)) ^ (col & 7)) << 4)]);
        }
#pragma unroll
        for (int mfa = 0; mfa < 2; ++mfa)
#pragma unroll
          for (int nf = 0; nf < 4; ++nf)
            gacc[mfa][nh * 4 + nf] =
                __builtin_amdgcn_mfma_f32_16x16x32_bf16(al[mfa], bw[nf], gacc[mfa][nh * 4 + nf], 0, 0, 0);
      }
    }
#pragma unroll
    for (int mfa = 0; mfa < 2; ++mfa)
#pragma unroll
      for (int nf = 0; nf < 8; ++nf) {
#pragma unroll
        for (int reg = 0; reg < 4; ++reg) {
          int res = resb + mfa * 16 + (l >> 4) * 4 + reg;
          int hc = hcb + nf * 16 + (l & 15);
          float sg = 1.f / (1.f + __expf(-gacc[mfa][nf][reg]));
          g_ws[(row0 + res) * HC + hc] = f2bf(sg);
        }
      }
  }
}

// ---------------------------------------------------------------------------
// K4 (MFMA, fused): unchanged except w_o staging is an identity copy from
// the pre-swizzled wo_img.
// ---------------------------------------------------------------------------
__global__ __launch_bounds__(512) void k_wavg(
    const unsigned short* __restrict__ Vt, const unsigned short* __restrict__ g_ws,
    const unsigned short* __restrict__ w_bf, const unsigned short* __restrict__ wo_img,
    float* __restrict__ out) {
  extern __shared__ char lds[];
  const int A_OFF = 0;       // 2 x 16384
  const int B_OFF = 32768;   // 2 x 6144
  const int P_OFF = 45056;   // 49152
  const int W_OFF = 94208;   // 32768
  int tid = threadIdx.x, l = tid & 63, wv = tid >> 6;
  int bs = blockIdx.x >> 2, bi = blockIdx.x & 3;
  int s0 = bs * 8, i0 = bi * 96;

  // stage w_o^T image (identity copy)
  {
    const int4* src = reinterpret_cast<const int4*>(wo_img);
    int4* dst = reinterpret_cast<int4*>(&lds[W_OFF]);
#pragma unroll
    for (int p = 0; p < 4; ++p) dst[p * 512 + tid] = src[p * 512 + tid];
  }

  int slotg = tid & 3;
  int rA0 = tid >> 2, rA1 = 128 + (tid >> 2);
  size_t vtb0 = ((size_t)(s0 + (rA0 >> 5)) * HC + (rA0 & 31)) * R_DIM + slotg * 8;
  size_t vtb1 = ((size_t)(s0 + (rA1 >> 5)) * HC + (rA1 & 31)) * R_DIM + slotg * 8;
  int ldsA0 = rA0 * 64 + ((slotg ^ (rA0 & 3)) << 4);
  int ldsA1 = rA1 * 64 + ((slotg ^ (rA1 & 3)) << 4);
  int rB = tid >> 2;
  size_t wbase = (size_t)(i0 + rB) * R_DIM + slotg * 8;
  int ldsB = rB * 64 + ((slotg ^ (rB & 3)) << 4);

  int aoff[4], boff[3], poff[6];
#pragma unroll
  for (int mf = 0; mf < 4; ++mf) {
    int row = ((wv & 3) * 4 + mf) * 16 + (l & 15);
    aoff[mf] = row * 64 + (((l >> 4) ^ (row & 3)) << 4);
  }
#pragma unroll
  for (int nf = 0; nf < 3; ++nf) {
    int row = ((wv >> 2) * 3 + nf) * 16 + (l & 15);
    boff[nf] = row * 64 + (((l >> 4) ^ (row & 3)) << 4);
  }
#pragma unroll
  for (int mf = 0; mf < 6; ++mf) {
    int row = (wv * 6 + mf) * 16 + (l & 15);
    poff[mf] = row * 64 + (((l >> 4) ^ (row & 3)) << 4);
  }

  f32x4 zz = {0.f, 0.f, 0.f, 0.f};
  f32x4 pacc[6][4];
#pragma unroll
  for (int a = 0; a < 6; ++a)
#pragma unroll
    for (int n = 0; n < 4; ++n) pacc[a][n] = zz;

  for (int h = 0; h < 8; ++h) {
    const unsigned short* VtA = Vt + (size_t)h * 32 * R_DIM;
    const unsigned short* WB = w_bf + (size_t)h * R_DIM * R_DIM;
    f32x4 acc[4][3];
#pragma unroll
    for (int a = 0; a < 4; ++a)
#pragma unroll
      for (int n = 0; n < 3; ++n) acc[a][n] = zz;

    {
      int4 va0 = *reinterpret_cast<const int4*>(VtA + vtb0);
      int4 va1 = *reinterpret_cast<const int4*>(VtA + vtb1);
      int4 vb;
      if (tid < 384) vb = *reinterpret_cast<const int4*>(WB + wbase);
      *reinterpret_cast<int4*>(&lds[A_OFF + ldsA0]) = va0;
      *reinterpret_cast<int4*>(&lds[A_OFF + ldsA1]) = va1;
      if (tid < 384) *reinterpret_cast<int4*>(&lds[B_OFF + ldsB]) = vb;
    }
    __syncthreads();

    for (int t = 0; t < 12; ++t) {
      int cur = t & 1;
      int4 va0, va1, vb;
      if (t < 11) {
        int j0n = (t + 1) * 32;
        va0 = *reinterpret_cast<const int4*>(VtA + vtb0 + j0n);
        va1 = *reinterpret_cast<const int4*>(VtA + vtb1 + j0n);
        if (tid < 384) vb = *reinterpret_cast<const int4*>(WB + wbase + j0n);
      }
      const char* ab = &lds[A_OFF + cur * 16384];
      const char* bb = &lds[B_OFF + cur * 6144];
      bf16x8 af[4], bfr[3];
#pragma unroll
      for (int mf = 0; mf < 4; ++mf) af[mf] = *reinterpret_cast<const bf16x8*>(ab + aoff[mf]);
#pragma unroll
      for (int nf = 0; nf < 3; ++nf) bfr[nf] = *reinterpret_cast<const bf16x8*>(bb + boff[nf]);
#pragma unroll
      for (int mf = 0; mf < 4; ++mf)
#pragma unroll
        for (int nf = 0; nf < 3; ++nf)
          acc[mf][nf] = __builtin_amdgcn_mfma_f32_16x16x32_bf16(af[mf], bfr[nf], acc[mf][nf], 0, 0, 0);
      if (t < 11) {
        int nxt = cur ^ 1;
        *reinterpret_cast<int4*>(&lds[A_OFF + nxt * 16384 + ldsA0]) = va0;
        *reinterpret_cast<int4*>(&lds[A_OFF + nxt * 16384 + ldsA1]) = va1;
        if (tid < 384) *reinterpret_cast<int4*>(&lds[B_OFF + nxt * 6144 + ldsB]) = vb;
      }
      __syncthreads();
    }

#pragma unroll
    for (int mf = 0; mf < 4; ++mf) {
      int MT = (wv & 3) * 4 + mf;
      int sl = MT >> 1;
      int c0 = (MT & 1) * 16 + (l >> 4) * 4;
#pragma unroll
      for (int nf = 0; nf < 3; ++nf) {
        int il = ((wv >> 2) * 3 + nf) * 16 + (l & 15);
        size_t gidx = ((size_t)(s0 + sl) * R_DIM + i0 + il) * HC + h * 32 + c0;
        ushort4 g4 = *reinterpret_cast<const ushort4*>(g_ws + gidx);
        int prow = sl * 96 + il;
        ushort4 og;
        og.x = f2bf(acc[mf][nf][0] * bf2f(g4.x));
        og.y = f2bf(acc[mf][nf][1] * bf2f(g4.y));
        og.z = f2bf(acc[mf][nf][2] * bf2f(g4.z));
        og.w = f2bf(acc[mf][nf][3] * bf2f(g4.w));
        *reinterpret_cast<ushort4*>(
            &lds[P_OFF + prow * 64 + (((c0 >> 3) ^ (prow & 3)) << 4) + (c0 & 7) * 2]) = og;
      }
    }
    __syncthreads();

    {
      bf16x8 pa[6], bw[4];
#pragma unroll
      for (int nt = 0; nt < 4; ++nt) {
        int lrow = nt * 16 + (l & 15);
        bw[nt] = *reinterpret_cast<const bf16x8*>(
            &lds[W_OFF + lrow * 512 + (((h * 4 + (l >> 4)) ^ (lrow & 7)) << 4)]);
      }
#pragma unroll
      for (int mf = 0; mf < 6; ++mf) pa[mf] = *reinterpret_cast<const bf16x8*>(&lds[P_OFF + poff[mf]]);
#pragma unroll
      for (int mf = 0; mf < 6; ++mf)
#pragma unroll
        for (int nt = 0; nt < 4; ++nt)
          pacc[mf][nt] = __builtin_amdgcn_mfma_f32_16x16x32_bf16(pa[mf], bw[nt], pacc[mf][nt], 0, 0, 0);
    }
    __syncthreads();
  }

#pragma unroll
  for (int mf = 0; mf < 6; ++mf) {
#pragma unroll
    for (int reg = 0; reg < 4; ++reg) {
      int prow = (wv * 6 + mf) * 16 + (l >> 4) * 4 + reg;
      int sl = prow / 96;
      int il = prow - sl * 96;
      size_t orow = (size_t)(s0 + sl) * R_DIM + i0 + il;
#pragma unroll
      for (int nt = 0; nt < 4; ++nt)
        out[orow * CMSA + nt * 16 + (l & 15)] = pacc[mf][nt][reg];
    }
  }
}

// ---------------------------------------------------------------------------
extern "C" void kernel_launch(void* const* d_in, const int* in_sizes, int n_in,
                              void* d_out, int out_size, void* d_ws, size_t ws_size,
                              hipStream_t stream) {
  (void)in_sizes; (void)n_in; (void)out_size; (void)ws_size;
  const float* m        = (const float*)d_in[0];
  const float* z        = (const float*)d_in[1];
  const float* msa_mask = (const float*)d_in[2];
  const float* z_mask   = (const float*)d_in[3];
  const float* ln_m_w   = (const float*)d_in[4];
  const float* ln_m_b   = (const float*)d_in[5];
  const float* ln_z_w   = (const float*)d_in[6];
  const float* ln_z_b   = (const float*)d_in[7];
  const float* w_v      = (const float*)d_in[8];
  const float* w_g      = (const float*)d_in[9];
  const float* w_b      = (const float*)d_in[10];
  const float* w_o      = (const float*)d_in[11];
  float* out = (float*)d_out;

  char* ws = (char*)d_ws;
  unsigned short* Vt   = (unsigned short*)ws;                     // 100,663,296 B
  unsigned short* g_ws = (unsigned short*)(ws + 100663296ull);    // 100,663,296 B
  float*          b_ws = (float*)(ws + 201326592ull);             //   4,718,592 B
  unsigned short* w_bf = (unsigned short*)(ws + 206045184ull);    //   2,359,296 B
  // weight images live in the b_ws region (dead after k_softmax): 3 x 32 KB
  unsigned short* wv_img = (unsigned short*)(ws + 201326592ull);
  unsigned short* wg_img = (unsigned short*)(ws + 201326592ull + 32768ull);
  unsigned short* wo_img = (unsigned short*)(ws + 201326592ull + 65536ull);

  k_bias<<<dim3(2304), dim3(256), 0, stream>>>(
      z, z_mask, ln_z_w, ln_z_b, w_b, b_ws);
  k_softmax<<<dim3(R_DIM * HH), dim3(128), 0, stream>>>(b_ws, w_bf);
  k_prep<<<dim3(24), dim3(256), 0, stream>>>(
      w_v, w_g, w_o, wv_img, wg_img, wo_img);
  k_vg<<<dim3(S_DIM * R_DIM / 128), dim3(512), 49664, stream>>>(
      m, msa_mask, ln_m_w, ln_m_b, wv_img, wg_img, Vt, g_ws);
  k_wavg<<<dim3(256), dim3(512), 126976, stream>>>(Vt, g_ws, w_bf, wo_img, out);
}